// Round 1
// baseline (153.072 us; speedup 1.0000x reference)
//
#include <hip/hip_runtime.h>

using bf16x8 = __attribute__((ext_vector_type(8))) short;
using f32x4  = __attribute__((ext_vector_type(4))) float;

#define DEVI __device__ __forceinline__

// round-to-nearest-even fp32 -> bf16 (bit pattern)
DEVI unsigned short f2bf(float f) {
  union { float ff; unsigned u; } v; v.ff = f;
  unsigned r = v.u + 0x7FFFu + ((v.u >> 16) & 1u);
  return (unsigned short)(r >> 16);
}

// async global->LDS, 16B per lane; l must be wave-uniform base (HW adds lane*16)
DEVI void g2l16(const void* g, void* l) {
  __builtin_amdgcn_global_load_lds(
      (const __attribute__((address_space(1))) unsigned int*)g,
      (__attribute__((address_space(3))) unsigned int*)l, 16, 0, 0);
}

// ---------------- x fp32 -> bf16 ----------------
__global__ void k_convx(const float* __restrict__ in, unsigned short* __restrict__ out, int n4) {
  int i = blockIdx.x * 256 + threadIdx.x;
  if (i >= n4) return;
  float4 v = reinterpret_cast<const float4*>(in)[i];
  ushort4 o;
  o.x = f2bf(v.x); o.y = f2bf(v.y); o.z = f2bf(v.z); o.w = f2bf(v.w);
  reinterpret_cast<ushort4*>(out)[i] = o;
}

// ---------------- transpose+convert: out[c][r] = bf16(in[r][c]) ----------------
__global__ void k_tconv(const float* __restrict__ in, unsigned short* __restrict__ out, int R, int C) {
  __shared__ float tile[32][33];
  int c0 = blockIdx.x * 32, r0 = blockIdx.y * 32;
  int x = threadIdx.x, y = threadIdx.y;  // block (32,8)
  for (int i = y; i < 32; i += 8) tile[i][x] = in[(size_t)(r0 + i) * C + c0 + x];
  __syncthreads();
  for (int i = y; i < 32; i += 8) out[(size_t)(c0 + i) * R + r0 + x] = f2bf(tile[x][i]);
}

// ---------------- QKV GEMM: [2048,1024] x [3072,1024]^T, epilogue scatters q/k/vT ----------------
__global__ __launch_bounds__(256) void k_gemm_qkv(
    const unsigned short* __restrict__ A, const unsigned short* __restrict__ Bt,
    const float* __restrict__ bias,
    unsigned short* __restrict__ qs, unsigned short* __restrict__ kbuf,
    unsigned short* __restrict__ vT) {
  constexpr int K = 1024;
  __shared__ __align__(16) unsigned short As[128 * 64];
  __shared__ __align__(16) unsigned short Bs[128 * 64];
  const int lane = threadIdx.x & 63, wid = threadIdx.x >> 6;
  const int m0 = blockIdx.y * 128, n0 = blockIdx.x * 128;
  const int wr = (wid >> 1) * 64, wc = (wid & 1) * 64;
  const int g = lane >> 4, li = lane & 15;
  f32x4 acc[4][4] = {};
  for (int k0 = 0; k0 < K; k0 += 64) {
    __syncthreads();
    for (int c = wid; c < 16; c += 4) {
      const int fb = c * 1024;
      const int flat = fb + lane * 16;
      const int row = flat >> 7, colb = flat & 127;
      g2l16((const char*)A  + ((size_t)(m0 + row) * K + k0) * 2 + colb, (char*)As + fb);
      g2l16((const char*)Bt + ((size_t)(n0 + row) * K + k0) * 2 + colb, (char*)Bs + fb);
    }
    __syncthreads();
#pragma unroll
    for (int ks = 0; ks < 2; ks++) {
      const int kk = ks * 32 + g * 8;
      bf16x8 a[4], b[4];
#pragma unroll
      for (int i = 0; i < 4; i++)
        a[i] = *reinterpret_cast<const bf16x8*>(As + (wr + i * 16 + li) * 64 + kk);
#pragma unroll
      for (int j = 0; j < 4; j++)
        b[j] = *reinterpret_cast<const bf16x8*>(Bs + (wc + j * 16 + li) * 64 + kk);
#pragma unroll
      for (int i = 0; i < 4; i++)
#pragma unroll
        for (int j = 0; j < 4; j++)
          acc[i][j] = __builtin_amdgcn_mfma_f32_16x16x32_bf16(a[i], b[j], acc[i][j], 0, 0, 0);
    }
  }
  const int rb = m0 + wr + g * 4;
  const int cb = n0 + wc + li;
#pragma unroll
  for (int j = 0; j < 4; j++) {
    const int c = cb + j * 16;
    const float bv = bias[c];
    const int hq = c >> 6, d = c & 63;
    const float sc = d < 32 ? 0.03125f : (d < 48 ? 0.0625f : 0.125f);
#pragma unroll
    for (int i = 0; i < 4; i++) {
#pragma unroll
      for (int r = 0; r < 4; r++) {
        const int t = rb + i * 16 + r;
        const float val = acc[i][j][r] + bv;
        if (c < 1024) {
          qs[((size_t)(hq * 2048 + t) << 6) + d] = f2bf(val * sc);
        } else if (c < 2048) {
          kbuf[((size_t)((hq - 16) * 2048 + t) << 6) + d] = f2bf(val);
        } else {
          vT[(size_t)((hq - 32) * 64 + d) * 2048 + t] = f2bf(val);
        }
      }
    }
  }
}

// ---------------- flash attention with hierarchical Keff ----------------
__global__ __launch_bounds__(256) void k_attn(
    const unsigned short* __restrict__ qs, const unsigned short* __restrict__ kbuf,
    const unsigned short* __restrict__ vT, unsigned short* __restrict__ yb) {
  __shared__ __align__(16) unsigned short Ks[128 * 64];   // [t2][d]
  __shared__ __align__(16) unsigned short Vs[64 * 128];   // [d][t2]
  __shared__ __align__(16) unsigned short Ps[128 * 128];  // [q'][t2]
  const int lane = threadIdx.x & 63, wid = threadIdx.x >> 6;
  const int g = lane >> 4, li = lane & 15;
  const int qt = blockIdx.x, h = blockIdx.y;
  const int q0 = qt * 128;
  const f32x4 fzero = {0.f, 0.f, 0.f, 0.f};
  const bf16x8 bzero = {0, 0, 0, 0, 0, 0, 0, 0};

  // Q fragments: wave owns rows [wid*32, wid*32+32)
  bf16x8 qf[2][2];
#pragma unroll
  for (int mi = 0; mi < 2; mi++)
#pragma unroll
    for (int ks = 0; ks < 2; ks++) {
      const int t = q0 + wid * 32 + mi * 16 + li;
      const int d = ks * 32 + g * 8;
      qf[mi][ks] = *reinterpret_cast<const bf16x8*>(qs + ((size_t)(h * 2048 + t) << 6) + d);
    }

  f32x4 o[2][4] = {};
  float m_run[8], l_run[8];
#pragma unroll
  for (int i = 0; i < 8; i++) { m_run[i] = -1e30f; l_run[i] = 0.f; }

  const int q256 = qt >> 1;
  for (int kt = 0; kt <= qt; kt++) {
    __syncthreads();
    // stage K tile [128][64] and V tile [64][128]
    for (int c = wid; c < 16; c += 4) {
      const int fb = c * 1024;
      const int flat = fb + lane * 16;
      {
        const int row = flat >> 7, colb = flat & 127;
        g2l16((const char*)kbuf + (((size_t)(h * 2048 + kt * 128 + row)) << 7) + colb,
              (char*)Ks + fb);
      }
      {
        const int row = flat >> 8, colb = flat & 255;
        g2l16((const char*)vT + ((size_t)(h * 64 + row) * 2048 + kt * 128) * 2 + colb,
              (char*)Vs + fb);
      }
    }
    __syncthreads();

    const int x = q256 ^ (kt >> 1);
    const int Keff = (x == 0) ? 64 : ((x >= 4) ? 32 : ((x >= 2) ? 48 : 56));

    // S = Q K^T over first Keff dims (scaling folded into q)
    f32x4 s[2][8];
#pragma unroll
    for (int mi = 0; mi < 2; mi++)
#pragma unroll
      for (int cf = 0; cf < 8; cf++) s[mi][cf] = fzero;

#pragma unroll
    for (int cf = 0; cf < 8; cf++) {
      const bf16x8 b0 = *reinterpret_cast<const bf16x8*>(Ks + (cf * 16 + li) * 64 + g * 8);
      s[0][cf] = __builtin_amdgcn_mfma_f32_16x16x32_bf16(qf[0][0], b0, s[0][cf], 0, 0, 0);
      s[1][cf] = __builtin_amdgcn_mfma_f32_16x16x32_bf16(qf[1][0], b0, s[1][cf], 0, 0, 0);
    }
    if (Keff > 32) {
      const bool zf = (32 + g * 8) >= Keff;
#pragma unroll
      for (int cf = 0; cf < 8; cf++) {
        bf16x8 b1 = *reinterpret_cast<const bf16x8*>(Ks + (cf * 16 + li) * 64 + 32 + g * 8);
        if (zf) b1 = bzero;
        s[0][cf] = __builtin_amdgcn_mfma_f32_16x16x32_bf16(qf[0][1], b1, s[0][cf], 0, 0, 0);
        s[1][cf] = __builtin_amdgcn_mfma_f32_16x16x32_bf16(qf[1][1], b1, s[1][cf], 0, 0, 0);
      }
    }

    // causal mask on the diagonal tile
    if (kt == qt) {
#pragma unroll
      for (int mi = 0; mi < 2; mi++)
#pragma unroll
        for (int cf = 0; cf < 8; cf++)
#pragma unroll
          for (int r = 0; r < 4; r++) {
            const int t1 = wid * 32 + mi * 16 + g * 4 + r;
            const int t2 = cf * 16 + li;
            if (t2 > t1) s[mi][cf][r] = -1e30f;
          }
    }

    // online softmax: row max + rescale
    float mnew[8], corr[8];
#pragma unroll
    for (int mi = 0; mi < 2; mi++)
#pragma unroll
      for (int r = 0; r < 4; r++) {
        float tm = s[mi][0][r];
#pragma unroll
        for (int cf = 1; cf < 8; cf++) tm = fmaxf(tm, s[mi][cf][r]);
        tm = fmaxf(tm, __shfl_xor(tm, 1));
        tm = fmaxf(tm, __shfl_xor(tm, 2));
        tm = fmaxf(tm, __shfl_xor(tm, 4));
        tm = fmaxf(tm, __shfl_xor(tm, 8));
        const int idx = mi * 4 + r;
        const float mn = fmaxf(m_run[idx], tm);
        mnew[idx] = mn;
        corr[idx] = __expf(m_run[idx] - mn);
        m_run[idx] = mn;
      }
    // P = exp(S - m), row sums, P -> LDS (A-fragment layout for PV)
#pragma unroll
    for (int mi = 0; mi < 2; mi++)
#pragma unroll
      for (int r = 0; r < 4; r++) {
        const int idx = mi * 4 + r;
        float sum = 0.f;
        const int rowoff = (wid * 32 + mi * 16 + g * 4 + r) * 128;
#pragma unroll
        for (int cf = 0; cf < 8; cf++) {
          const float p = __expf(s[mi][cf][r] - mnew[idx]);
          sum += p;
          Ps[rowoff + cf * 16 + li] = f2bf(p);
        }
        sum += __shfl_xor(sum, 1);
        sum += __shfl_xor(sum, 2);
        sum += __shfl_xor(sum, 4);
        sum += __shfl_xor(sum, 8);
        l_run[idx] = l_run[idx] * corr[idx] + sum;
      }
#pragma unroll
    for (int mi = 0; mi < 2; mi++)
#pragma unroll
      for (int nf = 0; nf < 4; nf++)
#pragma unroll
        for (int r = 0; r < 4; r++)
          o[mi][nf][r] *= corr[mi * 4 + r];

    __syncthreads();

    // O += P V
#pragma unroll
    for (int ks2 = 0; ks2 < 4; ks2++) {
      bf16x8 pa[2], vb[4];
#pragma unroll
      for (int mi = 0; mi < 2; mi++)
        pa[mi] = *reinterpret_cast<const bf16x8*>(Ps + (wid * 32 + mi * 16 + li) * 128 + ks2 * 32 + g * 8);
#pragma unroll
      for (int nf = 0; nf < 4; nf++)
        vb[nf] = *reinterpret_cast<const bf16x8*>(Vs + (nf * 16 + li) * 128 + ks2 * 32 + g * 8);
#pragma unroll
      for (int mi = 0; mi < 2; mi++)
#pragma unroll
        for (int nf = 0; nf < 4; nf++)
          o[mi][nf] = __builtin_amdgcn_mfma_f32_16x16x32_bf16(pa[mi], vb[nf], o[mi][nf], 0, 0, 0);
    }
  }

  // write y (bf16) in [t][h*64+d] layout for the proj GEMM
#pragma unroll
  for (int mi = 0; mi < 2; mi++)
#pragma unroll
    for (int nf = 0; nf < 4; nf++)
#pragma unroll
      for (int r = 0; r < 4; r++) {
        const int t = q0 + wid * 32 + mi * 16 + g * 4 + r;
        const int col = h * 64 + nf * 16 + li;
        yb[(size_t)t * 1024 + col] = f2bf(o[mi][nf][r] / l_run[mi * 4 + r]);
      }
}

// ---------------- proj GEMM: [2048,1024] x [1024,1024]^T -> fp32 out + bias ----------------
__global__ __launch_bounds__(256) void k_gemm_proj(
    const unsigned short* __restrict__ A, const unsigned short* __restrict__ Bt,
    const float* __restrict__ bias, float* __restrict__ out) {
  constexpr int K = 1024;
  __shared__ __align__(16) unsigned short As[128 * 64];
  __shared__ __align__(16) unsigned short Bs[128 * 64];
  const int lane = threadIdx.x & 63, wid = threadIdx.x >> 6;
  const int m0 = blockIdx.y * 128, n0 = blockIdx.x * 128;
  const int wr = (wid >> 1) * 64, wc = (wid & 1) * 64;
  const int g = lane >> 4, li = lane & 15;
  f32x4 acc[4][4] = {};
  for (int k0 = 0; k0 < K; k0 += 64) {
    __syncthreads();
    for (int c = wid; c < 16; c += 4) {
      const int fb = c * 1024;
      const int flat = fb + lane * 16;
      const int row = flat >> 7, colb = flat & 127;
      g2l16((const char*)A  + ((size_t)(m0 + row) * K + k0) * 2 + colb, (char*)As + fb);
      g2l16((const char*)Bt + ((size_t)(n0 + row) * K + k0) * 2 + colb, (char*)Bs + fb);
    }
    __syncthreads();
#pragma unroll
    for (int ks = 0; ks < 2; ks++) {
      const int kk = ks * 32 + g * 8;
      bf16x8 a[4], b[4];
#pragma unroll
      for (int i = 0; i < 4; i++)
        a[i] = *reinterpret_cast<const bf16x8*>(As + (wr + i * 16 + li) * 64 + kk);
#pragma unroll
      for (int j = 0; j < 4; j++)
        b[j] = *reinterpret_cast<const bf16x8*>(Bs + (wc + j * 16 + li) * 64 + kk);
#pragma unroll
      for (int i = 0; i < 4; i++)
#pragma unroll
        for (int j = 0; j < 4; j++)
          acc[i][j] = __builtin_amdgcn_mfma_f32_16x16x32_bf16(a[i], b[j], acc[i][j], 0, 0, 0);
    }
  }
  const int rb = m0 + wr + g * 4;
  const int cb = n0 + wc + li;
#pragma unroll
  for (int j = 0; j < 4; j++) {
    const int c = cb + j * 16;
    const float bv = bias[c];
#pragma unroll
    for (int i = 0; i < 4; i++) {
#pragma unroll
      for (int r = 0; r < 4; r++) {
        const int t = rb + i * 16 + r;
        out[(size_t)t * 1024 + c] = acc[i][j][r] + bv;
      }
    }
  }
}

extern "C" void kernel_launch(void* const* d_in, const int* in_sizes, int n_in,
                              void* d_out, int out_size, void* d_ws, size_t ws_size,
                              hipStream_t stream) {
  const float* x      = (const float*)d_in[0];
  const float* W_attn = (const float*)d_in[1];
  const float* b_attn = (const float*)d_in[2];
  const float* W_proj = (const float*)d_in[3];
  const float* b_proj = (const float*)d_in[4];
  float* out = (float*)d_out;
  char* ws = (char*)d_ws;
  const size_t MB = 1024 * 1024;
  unsigned short* xb  = (unsigned short*)(ws + 0 * MB);   // [2048][1024] bf16
  unsigned short* WaT = (unsigned short*)(ws + 4 * MB);   // [3072][1024] bf16
  unsigned short* WpT = (unsigned short*)(ws + 10 * MB);  // [1024][1024] bf16
  unsigned short* qs  = (unsigned short*)(ws + 12 * MB);  // [16][2048][64] bf16, pre-scaled
  unsigned short* kb  = (unsigned short*)(ws + 16 * MB);  // [16][2048][64] bf16
  unsigned short* vT  = (unsigned short*)(ws + 20 * MB);  // [16][64][2048] bf16
  unsigned short* yb  = (unsigned short*)(ws + 24 * MB);  // [2048][1024] bf16

  k_convx<<<dim3(2048), dim3(256), 0, stream>>>(x, xb, 524288);
  k_tconv<<<dim3(96, 32), dim3(32, 8), 0, stream>>>(W_attn, WaT, 1024, 3072);
  k_tconv<<<dim3(32, 32), dim3(32, 8), 0, stream>>>(W_proj, WpT, 1024, 1024);
  k_gemm_qkv<<<dim3(24, 16), dim3(256), 0, stream>>>(xb, WaT, b_attn, qs, kb, vT);
  k_attn<<<dim3(16, 16), dim3(256), 0, stream>>>(qs, kb, vT, yb);
  k_gemm_proj<<<dim3(8, 16), dim3(256), 0, stream>>>(yb, WpT, b_proj, out);
}

// Round 2
// 130.914 us; speedup vs baseline: 1.1693x; 1.1693x over previous
//
#include <hip/hip_runtime.h>

using bf16x8 = __attribute__((ext_vector_type(8))) short;
using f32x4  = __attribute__((ext_vector_type(4))) float;

#define DEVI __device__ __forceinline__

// round-to-nearest-even fp32 -> bf16 (bit pattern)
DEVI unsigned short f2bf(float f) {
  union { float ff; unsigned u; } v; v.ff = f;
  unsigned r = v.u + 0x7FFFu + ((v.u >> 16) & 1u);
  return (unsigned short)(r >> 16);
}

// async global->LDS, 16B per lane; l must be wave-uniform base (HW adds lane*16)
DEVI void g2l16(const void* g, void* l) {
  __builtin_amdgcn_global_load_lds(
      (const __attribute__((address_space(1))) unsigned int*)g,
      (__attribute__((address_space(3))) unsigned int*)l, 16, 0, 0);
}

// ---------------- x fp32 -> bf16 ----------------
__global__ void k_convx(const float* __restrict__ in, unsigned short* __restrict__ out, int n4) {
  int i = blockIdx.x * 256 + threadIdx.x;
  if (i >= n4) return;
  float4 v = reinterpret_cast<const float4*>(in)[i];
  ushort4 o;
  o.x = f2bf(v.x); o.y = f2bf(v.y); o.z = f2bf(v.z); o.w = f2bf(v.w);
  reinterpret_cast<ushort4*>(out)[i] = o;
}

// ---------------- transpose+convert: out[c][r] = bf16(in[r][c]) ----------------
__global__ void k_tconv(const float* __restrict__ in, unsigned short* __restrict__ out, int R, int C) {
  __shared__ float tile[32][33];
  int c0 = blockIdx.x * 32, r0 = blockIdx.y * 32;
  int x = threadIdx.x, y = threadIdx.y;  // block (32,8)
  for (int i = y; i < 32; i += 8) tile[i][x] = in[(size_t)(r0 + i) * C + c0 + x];
  __syncthreads();
  for (int i = y; i < 32; i += 8) out[(size_t)(c0 + i) * R + r0 + x] = f2bf(tile[x][i]);
}

// ---------------- QKV GEMM: [2048,1024] x [3072,1024]^T, epilogue scatters q/k/vT ----------------
__global__ __launch_bounds__(256) void k_gemm_qkv(
    const unsigned short* __restrict__ A, const unsigned short* __restrict__ Bt,
    const float* __restrict__ bias,
    unsigned short* __restrict__ qs, unsigned short* __restrict__ kbuf,
    unsigned short* __restrict__ vT) {
  constexpr int K = 1024;
  __shared__ __align__(16) unsigned short As[128 * 64];
  __shared__ __align__(16) unsigned short Bs[128 * 64];
  const int lane = threadIdx.x & 63, wid = threadIdx.x >> 6;
  const int m0 = blockIdx.y * 128, n0 = blockIdx.x * 128;
  const int wr = (wid >> 1) * 64, wc = (wid & 1) * 64;
  const int g = lane >> 4, li = lane & 15;
  f32x4 acc[4][4] = {};
  for (int k0 = 0; k0 < K; k0 += 64) {
    __syncthreads();
    for (int c = wid; c < 16; c += 4) {
      const int fb = c * 1024;
      const int flat = fb + lane * 16;
      const int row = flat >> 7, colb = flat & 127;
      g2l16((const char*)A  + ((size_t)(m0 + row) * K + k0) * 2 + colb, (char*)As + fb);
      g2l16((const char*)Bt + ((size_t)(n0 + row) * K + k0) * 2 + colb, (char*)Bs + fb);
    }
    __syncthreads();
#pragma unroll
    for (int ks = 0; ks < 2; ks++) {
      const int kk = ks * 32 + g * 8;
      bf16x8 a[4], b[4];
#pragma unroll
      for (int i = 0; i < 4; i++)
        a[i] = *reinterpret_cast<const bf16x8*>(As + (wr + i * 16 + li) * 64 + kk);
#pragma unroll
      for (int j = 0; j < 4; j++)
        b[j] = *reinterpret_cast<const bf16x8*>(Bs + (wc + j * 16 + li) * 64 + kk);
#pragma unroll
      for (int i = 0; i < 4; i++)
#pragma unroll
        for (int j = 0; j < 4; j++)
          acc[i][j] = __builtin_amdgcn_mfma_f32_16x16x32_bf16(a[i], b[j], acc[i][j], 0, 0, 0);
    }
  }
  const int rb = m0 + wr + g * 4;
  const int cb = n0 + wc + li;
#pragma unroll
  for (int j = 0; j < 4; j++) {
    const int c = cb + j * 16;
    const float bv = bias[c];
    const int hq = c >> 6, d = c & 63;
    const float sc = d < 32 ? 0.03125f : (d < 48 ? 0.0625f : 0.125f);
#pragma unroll
    for (int i = 0; i < 4; i++) {
#pragma unroll
      for (int r = 0; r < 4; r++) {
        const int t = rb + i * 16 + r;
        const float val = acc[i][j][r] + bv;
        if (c < 1024) {
          qs[((size_t)(hq * 2048 + t) << 6) + d] = f2bf(val * sc);
        } else if (c < 2048) {
          kbuf[((size_t)((hq - 16) * 2048 + t) << 6) + d] = f2bf(val);
        } else {
          vT[(size_t)((hq - 32) * 64 + d) * 2048 + t] = f2bf(val);
        }
      }
    }
  }
}

// per-head chunk offset table: off[qt] = sum_{j<qt} ceil((j+1)/4); off[16]=40
DEVI int chunk_off(int qt) {
  const int off[17] = {0,1,2,3,4,6,8,10,12,15,18,21,24,28,32,36,40};
  return off[qt];
}

// ---------------- flash attention partials: one block = (h, qt, chunk of <=4 K-tiles) ----------------
__global__ __launch_bounds__(256) void k_attn_part(
    const unsigned short* __restrict__ qs, const unsigned short* __restrict__ kbuf,
    const unsigned short* __restrict__ vT,
    float* __restrict__ o_part, float* __restrict__ ml) {
  __shared__ __align__(16) unsigned short Ks[128 * 64];   // [t2][d]
  __shared__ __align__(16) unsigned short Vs[64 * 128];   // [d][t2]
  __shared__ __align__(16) unsigned short Ps[128 * 128];  // [q'][t2]
  const int lane = threadIdx.x & 63, wid = threadIdx.x >> 6;
  const int g = lane >> 4, li = lane & 15;

  // decode work unit
  const int h = blockIdx.x / 40;
  const int rem = blockIdx.x % 40;
  int qt = 0;
#pragma unroll
  for (int i = 0; i < 16; i++)
    if (rem >= chunk_off(i + 1)) qt = i + 1;
  const int ci = rem - chunk_off(qt);
  const int kt0 = ci * 4;
  const int kt1 = min(qt, kt0 + 3);
  const int q0 = qt * 128;

  const f32x4 fzero = {0.f, 0.f, 0.f, 0.f};
  const bf16x8 bzero = {0, 0, 0, 0, 0, 0, 0, 0};

  // Q fragments: wave owns rows [wid*32, wid*32+32)
  bf16x8 qf[2][2];
#pragma unroll
  for (int mi = 0; mi < 2; mi++)
#pragma unroll
    for (int ks = 0; ks < 2; ks++) {
      const int t = q0 + wid * 32 + mi * 16 + li;
      const int d = ks * 32 + g * 8;
      qf[mi][ks] = *reinterpret_cast<const bf16x8*>(qs + ((size_t)(h * 2048 + t) << 6) + d);
    }

  f32x4 o[2][4] = {};
  float m_run[8], l_run[8];
#pragma unroll
  for (int i = 0; i < 8; i++) { m_run[i] = -1e30f; l_run[i] = 0.f; }

  const int q256 = qt >> 1;
  for (int kt = kt0; kt <= kt1; kt++) {
    __syncthreads();
    // stage K tile [128][64] and V tile [64][128]
    for (int c = wid; c < 16; c += 4) {
      const int fb = c * 1024;
      const int flat = fb + lane * 16;
      {
        const int row = flat >> 7, colb = flat & 127;
        g2l16((const char*)kbuf + (((size_t)(h * 2048 + kt * 128 + row)) << 7) + colb,
              (char*)Ks + fb);
      }
      {
        const int row = flat >> 8, colb = flat & 255;
        g2l16((const char*)vT + ((size_t)(h * 64 + row) * 2048 + kt * 128) * 2 + colb,
              (char*)Vs + fb);
      }
    }
    __syncthreads();

    const int x = q256 ^ (kt >> 1);
    const int Keff = (x == 0) ? 64 : ((x >= 4) ? 32 : ((x >= 2) ? 48 : 56));

    // S = Q K^T over first Keff dims (scaling folded into q)
    f32x4 s[2][8];
#pragma unroll
    for (int mi = 0; mi < 2; mi++)
#pragma unroll
      for (int cf = 0; cf < 8; cf++) s[mi][cf] = fzero;

#pragma unroll
    for (int cf = 0; cf < 8; cf++) {
      const bf16x8 b0 = *reinterpret_cast<const bf16x8*>(Ks + (cf * 16 + li) * 64 + g * 8);
      s[0][cf] = __builtin_amdgcn_mfma_f32_16x16x32_bf16(qf[0][0], b0, s[0][cf], 0, 0, 0);
      s[1][cf] = __builtin_amdgcn_mfma_f32_16x16x32_bf16(qf[1][0], b0, s[1][cf], 0, 0, 0);
    }
    if (Keff > 32) {
      const bool zf = (32 + g * 8) >= Keff;
#pragma unroll
      for (int cf = 0; cf < 8; cf++) {
        bf16x8 b1 = *reinterpret_cast<const bf16x8*>(Ks + (cf * 16 + li) * 64 + 32 + g * 8);
        if (zf) b1 = bzero;
        s[0][cf] = __builtin_amdgcn_mfma_f32_16x16x32_bf16(qf[0][1], b1, s[0][cf], 0, 0, 0);
        s[1][cf] = __builtin_amdgcn_mfma_f32_16x16x32_bf16(qf[1][1], b1, s[1][cf], 0, 0, 0);
      }
    }

    // causal mask on the diagonal tile
    if (kt == qt) {
#pragma unroll
      for (int mi = 0; mi < 2; mi++)
#pragma unroll
        for (int cf = 0; cf < 8; cf++)
#pragma unroll
          for (int r = 0; r < 4; r++) {
            const int t1 = wid * 32 + mi * 16 + g * 4 + r;
            const int t2 = cf * 16 + li;
            if (t2 > t1) s[mi][cf][r] = -1e30f;
          }
    }

    // online softmax: row max + rescale
    float mnew[8], corr[8];
#pragma unroll
    for (int mi = 0; mi < 2; mi++)
#pragma unroll
      for (int r = 0; r < 4; r++) {
        float tm = s[mi][0][r];
#pragma unroll
        for (int cf = 1; cf < 8; cf++) tm = fmaxf(tm, s[mi][cf][r]);
        tm = fmaxf(tm, __shfl_xor(tm, 1));
        tm = fmaxf(tm, __shfl_xor(tm, 2));
        tm = fmaxf(tm, __shfl_xor(tm, 4));
        tm = fmaxf(tm, __shfl_xor(tm, 8));
        const int idx = mi * 4 + r;
        const float mn = fmaxf(m_run[idx], tm);
        mnew[idx] = mn;
        corr[idx] = __expf(m_run[idx] - mn);
        m_run[idx] = mn;
      }
    // P = exp(S - m), row sums, P -> LDS (A-fragment layout for PV)
#pragma unroll
    for (int mi = 0; mi < 2; mi++)
#pragma unroll
      for (int r = 0; r < 4; r++) {
        const int idx = mi * 4 + r;
        float sum = 0.f;
        const int rowoff = (wid * 32 + mi * 16 + g * 4 + r) * 128;
#pragma unroll
        for (int cf = 0; cf < 8; cf++) {
          const float p = __expf(s[mi][cf][r] - mnew[idx]);
          sum += p;
          Ps[rowoff + cf * 16 + li] = f2bf(p);
        }
        sum += __shfl_xor(sum, 1);
        sum += __shfl_xor(sum, 2);
        sum += __shfl_xor(sum, 4);
        sum += __shfl_xor(sum, 8);
        l_run[idx] = l_run[idx] * corr[idx] + sum;
      }
#pragma unroll
    for (int mi = 0; mi < 2; mi++)
#pragma unroll
      for (int nf = 0; nf < 4; nf++)
#pragma unroll
        for (int r = 0; r < 4; r++)
          o[mi][nf][r] *= corr[mi * 4 + r];

    __syncthreads();

    // O += P V
#pragma unroll
    for (int ks2 = 0; ks2 < 4; ks2++) {
      bf16x8 pa[2], vb[4];
#pragma unroll
      for (int mi = 0; mi < 2; mi++)
        pa[mi] = *reinterpret_cast<const bf16x8*>(Ps + (wid * 32 + mi * 16 + li) * 128 + ks2 * 32 + g * 8);
#pragma unroll
      for (int nf = 0; nf < 4; nf++)
        vb[nf] = *reinterpret_cast<const bf16x8*>(Vs + (nf * 16 + li) * 128 + ks2 * 32 + g * 8);
#pragma unroll
      for (int mi = 0; mi < 2; mi++)
#pragma unroll
        for (int nf = 0; nf < 4; nf++)
          o[mi][nf] = __builtin_amdgcn_mfma_f32_16x16x32_bf16(pa[mi], vb[nf], o[mi][nf], 0, 0, 0);
    }
  }

  // write unnormalized partial O (fp32) + m,l
  const size_t pbase = (size_t)blockIdx.x * 8192;
#pragma unroll
  for (int mi = 0; mi < 2; mi++) {
#pragma unroll
    for (int nf = 0; nf < 4; nf++)
#pragma unroll
      for (int r = 0; r < 4; r++) {
        const int row = wid * 32 + mi * 16 + g * 4 + r;
        o_part[pbase + (size_t)row * 64 + nf * 16 + li] = o[mi][nf][r];
      }
  }
  if (li == 0) {
#pragma unroll
    for (int mi = 0; mi < 2; mi++)
#pragma unroll
      for (int r = 0; r < 4; r++) {
        const int row = wid * 32 + mi * 16 + g * 4 + r;
        ml[(size_t)blockIdx.x * 256 + row] = m_run[mi * 4 + r];
        ml[(size_t)blockIdx.x * 256 + 128 + row] = l_run[mi * 4 + r];
      }
  }
}

// ---------------- combine partials -> yb bf16 [t][h*64+d] ----------------
__global__ __launch_bounds__(256) void k_combine(
    const float* __restrict__ o_part, const float* __restrict__ ml,
    unsigned short* __restrict__ yb) {
  const int h = blockIdx.x >> 4, qt = blockIdx.x & 15;
  const int nc = (qt >> 2) + 1;
  const int base = h * 40 + chunk_off(qt);
  const int row = threadIdx.x >> 1;
  const int c0 = (threadIdx.x & 1) * 32;

  float m_i[4], l_i[4];
  float M = -1e30f;
  for (int ci = 0; ci < nc; ci++) {
    m_i[ci] = ml[(size_t)(base + ci) * 256 + row];
    l_i[ci] = ml[(size_t)(base + ci) * 256 + 128 + row];
    M = fmaxf(M, m_i[ci]);
  }
  float L = 0.f, w[4];
  for (int ci = 0; ci < nc; ci++) {
    w[ci] = __expf(m_i[ci] - M);
    L += w[ci] * l_i[ci];
  }
  const float inv = 1.0f / L;

  float acc[32];
#pragma unroll
  for (int j = 0; j < 32; j++) acc[j] = 0.f;
  for (int ci = 0; ci < nc; ci++) {
    const float* src = o_part + (size_t)(base + ci) * 8192 + (size_t)row * 64 + c0;
    const float wc = w[ci];
#pragma unroll
    for (int j4 = 0; j4 < 8; j4++) {
      float4 v = reinterpret_cast<const float4*>(src)[j4];
      acc[j4 * 4 + 0] += wc * v.x;
      acc[j4 * 4 + 1] += wc * v.y;
      acc[j4 * 4 + 2] += wc * v.z;
      acc[j4 * 4 + 3] += wc * v.w;
    }
  }
  const int t = qt * 128 + row;
  unsigned short* dst = yb + (size_t)t * 1024 + h * 64 + c0;
#pragma unroll
  for (int j8 = 0; j8 < 4; j8++) {
    ushort4 pk;
    pk.x = f2bf(acc[j8 * 8 + 0] * inv);
    pk.y = f2bf(acc[j8 * 8 + 1] * inv);
    pk.z = f2bf(acc[j8 * 8 + 2] * inv);
    pk.w = f2bf(acc[j8 * 8 + 3] * inv);
    ushort4 pk2;
    pk2.x = f2bf(acc[j8 * 8 + 4] * inv);
    pk2.y = f2bf(acc[j8 * 8 + 5] * inv);
    pk2.z = f2bf(acc[j8 * 8 + 6] * inv);
    pk2.w = f2bf(acc[j8 * 8 + 7] * inv);
    reinterpret_cast<ushort4*>(dst)[j8 * 2 + 0] = pk;
    reinterpret_cast<ushort4*>(dst)[j8 * 2 + 1] = pk2;
  }
}

// ---------------- proj GEMM: [2048,1024] x [1024,1024]^T -> fp32 out + bias ----------------
__global__ __launch_bounds__(256) void k_gemm_proj(
    const unsigned short* __restrict__ A, const unsigned short* __restrict__ Bt,
    const float* __restrict__ bias, float* __restrict__ out) {
  constexpr int K = 1024;
  __shared__ __align__(16) unsigned short As[128 * 64];
  __shared__ __align__(16) unsigned short Bs[128 * 64];
  const int lane = threadIdx.x & 63, wid = threadIdx.x >> 6;
  const int m0 = blockIdx.y * 128, n0 = blockIdx.x * 128;
  const int wr = (wid >> 1) * 64, wc = (wid & 1) * 64;
  const int g = lane >> 4, li = lane & 15;
  f32x4 acc[4][4] = {};
  for (int k0 = 0; k0 < K; k0 += 64) {
    __syncthreads();
    for (int c = wid; c < 16; c += 4) {
      const int fb = c * 1024;
      const int flat = fb + lane * 16;
      const int row = flat >> 7, colb = flat & 127;
      g2l16((const char*)A  + ((size_t)(m0 + row) * K + k0) * 2 + colb, (char*)As + fb);
      g2l16((const char*)Bt + ((size_t)(n0 + row) * K + k0) * 2 + colb, (char*)Bs + fb);
    }
    __syncthreads();
#pragma unroll
    for (int ks = 0; ks < 2; ks++) {
      const int kk = ks * 32 + g * 8;
      bf16x8 a[4], b[4];
#pragma unroll
      for (int i = 0; i < 4; i++)
        a[i] = *reinterpret_cast<const bf16x8*>(As + (wr + i * 16 + li) * 64 + kk);
#pragma unroll
      for (int j = 0; j < 4; j++)
        b[j] = *reinterpret_cast<const bf16x8*>(Bs + (wc + j * 16 + li) * 64 + kk);
#pragma unroll
      for (int i = 0; i < 4; i++)
#pragma unroll
        for (int j = 0; j < 4; j++)
          acc[i][j] = __builtin_amdgcn_mfma_f32_16x16x32_bf16(a[i], b[j], acc[i][j], 0, 0, 0);
    }
  }
  const int rb = m0 + wr + g * 4;
  const int cb = n0 + wc + li;
#pragma unroll
  for (int j = 0; j < 4; j++) {
    const int c = cb + j * 16;
    const float bv = bias[c];
#pragma unroll
    for (int i = 0; i < 4; i++) {
#pragma unroll
      for (int r = 0; r < 4; r++) {
        const int t = rb + i * 16 + r;
        out[(size_t)t * 1024 + c] = acc[i][j][r] + bv;
      }
    }
  }
}

extern "C" void kernel_launch(void* const* d_in, const int* in_sizes, int n_in,
                              void* d_out, int out_size, void* d_ws, size_t ws_size,
                              hipStream_t stream) {
  const float* x      = (const float*)d_in[0];
  const float* W_attn = (const float*)d_in[1];
  const float* b_attn = (const float*)d_in[2];
  const float* W_proj = (const float*)d_in[3];
  const float* b_proj = (const float*)d_in[4];
  float* out = (float*)d_out;
  char* ws = (char*)d_ws;
  const size_t MB = 1024 * 1024;
  unsigned short* xb  = (unsigned short*)(ws + 0 * MB);   // [2048][1024] bf16
  unsigned short* WaT = (unsigned short*)(ws + 4 * MB);   // [3072][1024] bf16
  unsigned short* WpT = (unsigned short*)(ws + 10 * MB);  // [1024][1024] bf16
  unsigned short* qs  = (unsigned short*)(ws + 12 * MB);  // [16][2048][64] bf16, pre-scaled
  unsigned short* kb  = (unsigned short*)(ws + 16 * MB);  // [16][2048][64] bf16
  unsigned short* vT  = (unsigned short*)(ws + 20 * MB);  // [16][64][2048] bf16
  unsigned short* yb  = (unsigned short*)(ws + 24 * MB);  // [2048][1024] bf16
  float* o_part = (float*)(ws + 28 * MB);                 // [640][128][64] fp32 (20 MB)
  float* ml     = (float*)(ws + 48 * MB + 256 * 1024);    // [640][2][128] fp32

  k_convx<<<dim3(2048), dim3(256), 0, stream>>>(x, xb, 524288);
  k_tconv<<<dim3(96, 32), dim3(32, 8), 0, stream>>>(W_attn, WaT, 1024, 3072);
  k_tconv<<<dim3(32, 32), dim3(32, 8), 0, stream>>>(W_proj, WpT, 1024, 1024);
  k_gemm_qkv<<<dim3(24, 16), dim3(256), 0, stream>>>(xb, WaT, b_attn, qs, kb, vT);
  k_attn_part<<<dim3(640), dim3(256), 0, stream>>>(qs, kb, vT, o_part, ml);
  k_combine<<<dim3(256), dim3(256), 0, stream>>>(o_part, ml, yb);
  k_gemm_proj<<<dim3(8, 16), dim3(256), 0, stream>>>(yb, WpT, b_proj, out);
}